// Round 1
// baseline (20.423 us; speedup 1.0000x reference)
//
#include <hip/hip_runtime.h>

// DecorrelationPatch2d: out[n,c,y,x] = x[n,c,y,x] * S(c,y,x) / div(y,x)
//   s[k] = sum_m R[k,m]  (k = c*9 + 3*i + j)
//   S    = sum over valid (i,j) of s[c*9+3i+j]
//   div  = (#valid i) * (#valid j)
// Valid i: max(0, y-125) <= i <= min(2, y)   (H=128, Ho=126, KH=3)

#define NCH 64
#define HW  128
#define PL  576   // patch length = 64*3*3

// --- kernel 1: s[row] = sum of R[row, :] ------------------------------------
__global__ __launch_bounds__(64) void rowsum_kernel(const float* __restrict__ R,
                                                    float* __restrict__ s) {
    const int row  = blockIdx.x;     // 0..575
    const int lane = threadIdx.x;    // 0..63
    float acc = 0.f;
    #pragma unroll
    for (int m = 0; m < PL; m += 64)
        acc += R[row * PL + m + lane];
    #pragma unroll
    for (int off = 32; off > 0; off >>= 1)
        acc += __shfl_down(acc, off, 64);
    if (lane == 0) s[row] = acc;
}

// --- kernel 2: pointwise scale, one float4 per thread -----------------------
__global__ __launch_bounds__(256) void decor_kernel(const float* __restrict__ x,
                                                    const float* __restrict__ s,
                                                    float* __restrict__ out) {
    const int idx4 = blockIdx.x * 256 + threadIdx.x;  // float4 index
    // layout (float4 units): ((n*64 + c)*128 + y)*32 + x4
    const int x4 = idx4 & 31;
    const int t  = idx4 >> 5;
    const int y  = t & 127;
    const int c  = (t >> 7) & 63;

    // load the channel's 3x3 s-block (wave-uniform c -> broadcast, L2-hot)
    const float* __restrict__ s9 = s + c * 9;
    const float a0 = s9[0], a1 = s9[1], a2 = s9[2];
    const float a3 = s9[3], a4 = s9[4], a5 = s9[5];
    const float a6 = s9[6], a7 = s9[7], a8 = s9[8];

    // valid-i selection for this row (branch-free)
    const bool i0 = (y <= 125);
    const bool i1 = (y >= 1) && (y <= 126);
    const bool i2 = (y >= 2);
    const float col0 = (i0 ? a0 : 0.f) + (i1 ? a3 : 0.f) + (i2 ? a6 : 0.f);
    const float col1 = (i0 ? a1 : 0.f) + (i1 ? a4 : 0.f) + (i2 ? a7 : 0.f);
    const float col2 = (i0 ? a2 : 0.f) + (i1 ? a5 : 0.f) + (i2 ? a8 : 0.f);
    const int ny = (int)i0 + (int)i1 + (int)i2;

    const float4 v = reinterpret_cast<const float4*>(x)[idx4];
    float r[4] = {v.x, v.y, v.z, v.w};

    #pragma unroll
    for (int e = 0; e < 4; ++e) {
        const int xx = x4 * 4 + e;
        const bool j0 = (xx <= 125);
        const bool j1 = (xx >= 1) && (xx <= 126);
        const bool j2 = (xx >= 2);
        const float rowsum = (j0 ? col0 : 0.f) + (j1 ? col1 : 0.f)
                           + (j2 ? col2 : 0.f);
        const int nx = (int)j0 + (int)j1 + (int)j2;
        r[e] = r[e] * rowsum / (float)(ny * nx);
    }

    float4 o;
    o.x = r[0]; o.y = r[1]; o.z = r[2]; o.w = r[3];
    reinterpret_cast<float4*>(out)[idx4] = o;
}

extern "C" void kernel_launch(void* const* d_in, const int* in_sizes, int n_in,
                              void* d_out, int out_size, void* d_ws, size_t ws_size,
                              hipStream_t stream) {
    const float* x = (const float*)d_in[0];   // [8,64,128,128] fp32
    const float* R = (const float*)d_in[1];   // [576,576] fp32
    float* out = (float*)d_out;               // [8,64,128,128] fp32
    float* s   = (float*)d_ws;                // 576 floats scratch

    rowsum_kernel<<<PL, 64, 0, stream>>>(R, s);

    const int n4 = out_size / 4;              // 2,097,152 float4
    decor_kernel<<<n4 / 256, 256, 0, stream>>>(x, s, out);
}

// Round 2
// 16.990 us; speedup vs baseline: 1.2021x; 1.2021x over previous
//
#include <hip/hip_runtime.h>

// DecorrelationPatch2d, fused single kernel.
// out[n,c,y,x] = x[n,c,y,x] * ( sum_{valid i,j} s[c*9+3i+j] ) / (ny*nx)
//   s[k] = sum_m R[k,m];  valid i: max(0,y-125) <= i <= min(2,y)  (H=128, KH=3)
// Each block owns half a (n,c) plane (64 rows x 128 cols) and computes its own
// 9 row-sums of R from L2 (R = 1.3 MB, L2-resident; 21 MB total replicated
// traffic, hidden under the 67 MB HBM stream).

#define PL 576   // patch length = 64*3*3

__global__ __launch_bounds__(256) void decor_fused(const float* __restrict__ x,
                                                   const float* __restrict__ R,
                                                   float* __restrict__ out) {
    __shared__ float s9[9];
    const int tid  = threadIdx.x;
    const int b    = blockIdx.x;       // 0..1023
    const int nc   = b >> 1;           // n*64 + c
    const int half = b & 1;            // top / bottom half of the plane
    const int c    = nc & 63;
    const int base4 = nc * 4096 + half * 2048;   // float4 index of block start

    // ---- issue the block's 8 independent x-loads first (hide HBM latency
    //      under the R reduction) ----
    const float4* __restrict__ x4p = reinterpret_cast<const float4*>(x);
    float4 v0 = x4p[base4 + 0 * 256 + tid];
    float4 v1 = x4p[base4 + 1 * 256 + tid];
    float4 v2 = x4p[base4 + 2 * 256 + tid];
    float4 v3 = x4p[base4 + 3 * 256 + tid];
    float4 v4 = x4p[base4 + 4 * 256 + tid];
    float4 v5 = x4p[base4 + 5 * 256 + tid];
    float4 v6 = x4p[base4 + 6 * 256 + tid];
    float4 v7 = x4p[base4 + 7 * 256 + tid];

    // ---- phase 1: s9[r] = sum over 576 cols of R[c*9 + r] (L2-hot) ----
    const int wave = tid >> 6, lane = tid & 63;
    for (int r = wave; r < 9; r += 4) {
        const float* __restrict__ row = R + (c * 9 + r) * PL;
        float acc = 0.f;
        #pragma unroll
        for (int m = 0; m < PL; m += 64) acc += row[m + lane];
        #pragma unroll
        for (int off = 32; off > 0; off >>= 1) acc += __shfl_down(acc, off, 64);
        if (lane == 0) s9[r] = acc;
    }
    __syncthreads();

    const float a0 = s9[0], a1 = s9[1], a2 = s9[2];
    const float a3 = s9[3], a4 = s9[4], a5 = s9[5];
    const float a6 = s9[6], a7 = s9[7], a8 = s9[8];

    // ---- per-element x (column) predicates: constant across iterations ----
    const int x4i = tid & 31;
    float jw0[4], jw1[4], jw2[4], invnx[4];   // fully unrolled -> registers
    #pragma unroll
    for (int e = 0; e < 4; ++e) {
        const int xx = x4i * 4 + e;
        const bool j0 = (xx <= 125);
        const bool j1 = (xx >= 1) && (xx <= 126);
        const bool j2 = (xx >= 2);
        jw0[e] = j0 ? 1.f : 0.f;
        jw1[e] = j1 ? 1.f : 0.f;
        jw2[e] = j2 ? 1.f : 0.f;
        const int nx = (int)j0 + (int)j1 + (int)j2;
        invnx[e] = (nx == 3) ? (1.f / 3.f) : ((nx == 2) ? 0.5f : 1.f);
    }

    // ---- phase 2: scale + store; y advances by 8 per iteration ----
    const int yb = half * 64 + (tid >> 5);
    float4* __restrict__ o4p = reinterpret_cast<float4*>(out);
    float4 vv[8] = {v0, v1, v2, v3, v4, v5, v6, v7};
    #pragma unroll
    for (int it = 0; it < 8; ++it) {
        const int y = yb + it * 8;
        const bool i0 = (y <= 125);
        const bool i1 = (y >= 1) && (y <= 126);
        const bool i2 = (y >= 2);
        const int ny = (int)i0 + (int)i1 + (int)i2;
        const float invny = (ny == 3) ? (1.f / 3.f) : ((ny == 2) ? 0.5f : 1.f);
        const float f0 = ((i0 ? a0 : 0.f) + (i1 ? a3 : 0.f) + (i2 ? a6 : 0.f)) * invny;
        const float f1 = ((i0 ? a1 : 0.f) + (i1 ? a4 : 0.f) + (i2 ? a7 : 0.f)) * invny;
        const float f2 = ((i0 ? a2 : 0.f) + (i1 ? a5 : 0.f) + (i2 ? a8 : 0.f)) * invny;

        float r[4] = {vv[it].x, vv[it].y, vv[it].z, vv[it].w};
        #pragma unroll
        for (int e = 0; e < 4; ++e) {
            const float factor = (jw0[e] * f0 + jw1[e] * f1 + jw2[e] * f2) * invnx[e];
            r[e] *= factor;
        }
        float4 o;
        o.x = r[0]; o.y = r[1]; o.z = r[2]; o.w = r[3];
        o4p[base4 + it * 256 + tid] = o;
    }
}

extern "C" void kernel_launch(void* const* d_in, const int* in_sizes, int n_in,
                              void* d_out, int out_size, void* d_ws, size_t ws_size,
                              hipStream_t stream) {
    const float* x = (const float*)d_in[0];   // [8,64,128,128] fp32
    const float* R = (const float*)d_in[1];   // [576,576] fp32
    float* out = (float*)d_out;               // [8,64,128,128] fp32
    (void)d_ws; (void)ws_size;

    decor_fused<<<1024, 256, 0, stream>>>(x, R, out);
}

// Round 3
// 16.788 us; speedup vs baseline: 1.2166x; 1.0121x over previous
//
#include <hip/hip_runtime.h>

// DecorrelationPatch2d, fused single kernel, one block per (n,c) plane.
// out[n,c,y,x] = x[n,c,y,x] * ( sum_{valid i,j} s[c*9+3i+j] ) / (ny*nx)
//   s[k] = sum_m R[k,m];  valid i: max(0,y-125) <= i <= min(2,y)  (H=128, KH=3)
// 512 blocks x 512 threads; each block computes its channel's 9 R-row-sums
// (float4 loads, wave-per-row shuffle reduce; R is L2-resident) while its
// 8 x-loads/thread are in flight, then scales + stores.

#define PL 576   // patch length = 64*3*3

__global__ __launch_bounds__(512) void decor_fused(const float* __restrict__ x,
                                                   const float* __restrict__ R,
                                                   float* __restrict__ out) {
    __shared__ float s9[9];
    const int tid   = threadIdx.x;        // 0..511
    const int b     = blockIdx.x;         // 0..511 == plane (n*64 + c)
    const int c     = b & 63;
    const int base4 = b * 4096;           // float4 index of plane start

    // ---- issue the 8 independent x-loads first (hide HBM latency under the
    //      R reduction) ----
    const float4* __restrict__ x4p = reinterpret_cast<const float4*>(x);
    float4 v0 = x4p[base4 + 0 * 512 + tid];
    float4 v1 = x4p[base4 + 1 * 512 + tid];
    float4 v2 = x4p[base4 + 2 * 512 + tid];
    float4 v3 = x4p[base4 + 3 * 512 + tid];
    float4 v4 = x4p[base4 + 4 * 512 + tid];
    float4 v5 = x4p[base4 + 5 * 512 + tid];
    float4 v6 = x4p[base4 + 6 * 512 + tid];
    float4 v7 = x4p[base4 + 7 * 512 + tid];

    // ---- phase 1: s9[r] = sum of R[c*9+r, :]  (wave r does row r; wave 0
    //      also row 8; float4 loads: 144 f4/row over 64 lanes) ----
    const int wave = tid >> 6, lane = tid & 63;
    for (int r = wave; r < 9; r += 8) {
        const float4* __restrict__ row4 =
            reinterpret_cast<const float4*>(R + (c * 9 + r) * PL);
        float4 p = row4[lane];
        float4 q = row4[lane + 64];
        float acc = (p.x + p.y) + (p.z + p.w) + (q.x + q.y) + (q.z + q.w);
        if (lane < 16) {
            float4 u = row4[lane + 128];
            acc += (u.x + u.y) + (u.z + u.w);
        }
        #pragma unroll
        for (int off = 32; off > 0; off >>= 1) acc += __shfl_down(acc, off, 64);
        if (lane == 0) s9[r] = acc;
    }
    __syncthreads();

    const float a0 = s9[0], a1 = s9[1], a2 = s9[2];
    const float a3 = s9[3], a4 = s9[4], a5 = s9[5];
    const float a6 = s9[6], a7 = s9[7], a8 = s9[8];

    // ---- per-element x (column) predicates: constant across iterations ----
    const int x4i = tid & 31;
    float jw0[4], jw1[4], jw2[4], invnx[4];   // fully unrolled -> registers
    #pragma unroll
    for (int e = 0; e < 4; ++e) {
        const int xx = x4i * 4 + e;
        const bool j0 = (xx <= 125);
        const bool j1 = (xx >= 1) && (xx <= 126);
        const bool j2 = (xx >= 2);
        jw0[e] = j0 ? 1.f : 0.f;
        jw1[e] = j1 ? 1.f : 0.f;
        jw2[e] = j2 ? 1.f : 0.f;
        const int nx = (int)j0 + (int)j1 + (int)j2;
        invnx[e] = (nx == 3) ? (1.f / 3.f) : ((nx == 2) ? 0.5f : 1.f);
    }

    // ---- phase 2: scale + store; y = k*16 + tid/32 ----
    const int yb = tid >> 5;
    float4* __restrict__ o4p = reinterpret_cast<float4*>(out);
    float4 vv[8] = {v0, v1, v2, v3, v4, v5, v6, v7};
    #pragma unroll
    for (int k = 0; k < 8; ++k) {
        const int y = k * 16 + yb;
        const bool i0 = (y <= 125);
        const bool i1 = (y >= 1) && (y <= 126);
        const bool i2 = (y >= 2);
        const int ny = (int)i0 + (int)i1 + (int)i2;
        const float invny = (ny == 3) ? (1.f / 3.f) : ((ny == 2) ? 0.5f : 1.f);
        const float f0 = ((i0 ? a0 : 0.f) + (i1 ? a3 : 0.f) + (i2 ? a6 : 0.f)) * invny;
        const float f1 = ((i0 ? a1 : 0.f) + (i1 ? a4 : 0.f) + (i2 ? a7 : 0.f)) * invny;
        const float f2 = ((i0 ? a2 : 0.f) + (i1 ? a5 : 0.f) + (i2 ? a8 : 0.f)) * invny;

        float r[4] = {vv[k].x, vv[k].y, vv[k].z, vv[k].w};
        #pragma unroll
        for (int e = 0; e < 4; ++e) {
            const float factor = (jw0[e] * f0 + jw1[e] * f1 + jw2[e] * f2) * invnx[e];
            r[e] *= factor;
        }
        float4 o;
        o.x = r[0]; o.y = r[1]; o.z = r[2]; o.w = r[3];
        o4p[base4 + k * 512 + tid] = o;
    }
}

extern "C" void kernel_launch(void* const* d_in, const int* in_sizes, int n_in,
                              void* d_out, int out_size, void* d_ws, size_t ws_size,
                              hipStream_t stream) {
    const float* x = (const float*)d_in[0];   // [8,64,128,128] fp32
    const float* R = (const float*)d_in[1];   // [576,576] fp32
    float* out = (float*)d_out;               // [8,64,128,128] fp32
    (void)d_ws; (void)ws_size;

    decor_fused<<<512, 512, 0, stream>>>(x, R, out);
}